// Round 2
// baseline (191.833 us; speedup 1.0000x reference)
//
#include <hip/hip_runtime.h>

#define NSTEPS 21
#define DT_F 0.05f

// tanh(x) = 1 - 2/(1 + 2^(x * 2*log2(e))); single v_mul + v_exp_f32 + v_rcp_f32.
// Saturates correctly: exp2->inf => 1, exp2->0 => -1.
__device__ __forceinline__ float fast_tanh(float x) {
    float e = __builtin_amdgcn_exp2f(x * 2.88539008177793f);
    return 1.0f - 2.0f * __builtin_amdgcn_rcpf(1.0f + e);
}

__global__ __launch_bounds__(256) void rollout_kernel(
    const float* __restrict__ omega, const float* __restrict__ s0p,
    const float* __restrict__ Wh1, const float* __restrict__ bh1,
    const float* __restrict__ Wh2, const float* __restrict__ bh2,
    const float* __restrict__ Wr1, const float* __restrict__ br1,
    const float* __restrict__ Wr2, const float* __restrict__ br2,
    float* __restrict__ block_sums, int N)
{
    const int tid = blockIdx.x * blockDim.x + threadIdx.x;

    float cost = 0.0f;
    if (tid < N) {
        const float tgt0 = omega[tid];        // omega row 0: target pos
        const float tgt1 = omega[N + tid];    // omega row 1: target vel
        float sv0 = s0p[0];
        float sv1 = s0p[1];

        // human layer 1: columns 0,1 multiply constant s_star -> hoist out of loop.
        const float w02 = Wh1[2],  w03 = Wh1[3];
        const float w12 = Wh1[6],  w13 = Wh1[7];
        const float w22 = Wh1[10], w23 = Wh1[11];
        const float w32 = Wh1[14], w33 = Wh1[15];
        const float hp0 = Wh1[0]  * tgt0 + Wh1[1]  * tgt1 + bh1[0];
        const float hp1 = Wh1[4]  * tgt0 + Wh1[5]  * tgt1 + bh1[1];
        const float hp2 = Wh1[8]  * tgt0 + Wh1[9]  * tgt1 + bh1[2];
        const float hp3 = Wh1[12] * tgt0 + Wh1[13] * tgt1 + bh1[3];
        const float u0 = Wh2[0], u1 = Wh2[1], u2 = Wh2[2], u3 = Wh2[3], ub = bh2[0];
        const float r00 = Wr1[0], r01 = Wr1[1], r02 = Wr1[2], rb0 = br1[0];
        const float r10 = Wr1[3], r11 = Wr1[4], r12 = Wr1[5], rb1 = br1[1];
        const float r20 = Wr1[6], r21 = Wr1[7], r22 = Wr1[8], rb2 = br1[2];
        const float v0 = Wr2[0], v1 = Wr2[1], v2 = Wr2[2], vb = br2[0];

        float err = 0.0f, eff = 0.0f;
        #pragma unroll
        for (int t = 0; t < NSTEPS - 1; ++t) {
            float e0 = tgt0 - sv0;
            float e1 = tgt1 - sv1;
            err += 10.0f * e0 * e0 + e1 * e1;
            float h0 = fast_tanh(hp0 + w02 * sv0 + w03 * sv1);
            float h1 = fast_tanh(hp1 + w12 * sv0 + w13 * sv1);
            float h2 = fast_tanh(hp2 + w22 * sv0 + w23 * sv1);
            float h3 = fast_tanh(hp3 + w32 * sv0 + w33 * sv1);
            float z  = ub + u0 * h0 + u1 * h1 + u2 * h2 + u3 * h3;
            eff += z * z;
            float q0 = fast_tanh(rb0 + r00 * sv0 + r01 * sv1 + r02 * z);
            float q1 = fast_tanh(rb1 + r10 * sv0 + r11 * sv1 + r12 * z);
            float q2 = fast_tanh(rb2 + r20 * sv0 + r21 * sv1 + r22 * z);
            float a  = vb + v0 * q0 + v1 * q1 + v2 * q2;
            float ns0 = sv0 + DT_F * sv1;   // uses OLD sv1
            float ns1 = sv1 + DT_F * a;
            sv0 = ns0; sv1 = ns1;
        }
        float e0 = tgt0 - sv0;
        float e1 = tgt1 - sv1;
        err += 10.0f * e0 * e0 + e1 * e1;   // terminal cost
        cost = err + eff;
    }

    // wave (64-lane) reduce, then cross-wave via LDS
    #pragma unroll
    for (int off = 32; off > 0; off >>= 1)
        cost += __shfl_down(cost, off, 64);
    __shared__ float ws[4];
    const int lane = threadIdx.x & 63;
    const int wid  = threadIdx.x >> 6;
    if (lane == 0) ws[wid] = cost;
    __syncthreads();
    if (threadIdx.x == 0)
        block_sums[blockIdx.x] = ws[0] + ws[1] + ws[2] + ws[3];
}

__global__ __launch_bounds__(256) void final_reduce(
    const float* __restrict__ block_sums, int nb, int N, float* __restrict__ out)
{
    double s = 0.0;
    for (int i = threadIdx.x; i < nb; i += 256)
        s += (double)block_sums[i];
    #pragma unroll
    for (int off = 32; off > 0; off >>= 1)
        s += __shfl_down(s, off, 64);
    __shared__ double ws[4];
    const int lane = threadIdx.x & 63;
    const int wid  = threadIdx.x >> 6;
    if (lane == 0) ws[wid] = s;
    __syncthreads();
    if (threadIdx.x == 0) {
        double tot = ws[0] + ws[1] + ws[2] + ws[3];
        out[0] = (float)(tot / (double)N);
    }
}

extern "C" void kernel_launch(void* const* d_in, const int* in_sizes, int n_in,
                              void* d_out, int out_size, void* d_ws, size_t ws_size,
                              hipStream_t stream) {
    const float* omega = (const float*)d_in[0];
    const float* s0    = (const float*)d_in[1];
    const float* Wh1   = (const float*)d_in[2];
    const float* bh1   = (const float*)d_in[3];
    const float* Wh2   = (const float*)d_in[4];
    const float* bh2   = (const float*)d_in[5];
    const float* Wr1   = (const float*)d_in[6];
    const float* br1   = (const float*)d_in[7];
    const float* Wr2   = (const float*)d_in[8];
    const float* br2   = (const float*)d_in[9];
    float* out = (float*)d_out;
    float* block_sums = (float*)d_ws;   // blocks * 4 bytes, well under ws_size

    const int N = in_sizes[0] / 2;
    const int blocks = (N + 255) / 256;
    rollout_kernel<<<blocks, 256, 0, stream>>>(omega, s0, Wh1, bh1, Wh2, bh2,
                                               Wr1, br1, Wr2, br2, block_sums, N);
    final_reduce<<<1, 256, 0, stream>>>(block_sums, blocks, N, out);
}

// Round 3
// 151.599 us; speedup vs baseline: 1.2654x; 1.2654x over previous
//
#include <hip/hip_runtime.h>

#define NSTEPS 21
#define DT_F 0.05f

typedef float f32x2 __attribute__((ext_vector_type(2)));

__device__ __forceinline__ f32x2 sp(float s) { return (f32x2){s, s}; }

// tanh(x) = 1 - 2/(1 + 2^(x*2*log2 e)); exp/rcp are scalar-only (no packed trans),
// everything else vectorizes to v_pk_* ops.
__device__ __forceinline__ f32x2 ftanh2(f32x2 x) {
    f32x2 e, r;
    e.x = __builtin_amdgcn_exp2f(x.x * 2.885390081777927f);
    e.y = __builtin_amdgcn_exp2f(x.y * 2.885390081777927f);
    r.x = __builtin_amdgcn_rcpf(1.0f + e.x);
    r.y = __builtin_amdgcn_rcpf(1.0f + e.y);
    return sp(1.0f) - sp(2.0f) * r;
}

__global__ __launch_bounds__(256) void rollout_kernel(
    const float* __restrict__ omega, const float* __restrict__ s0p,
    const float* __restrict__ Wh1, const float* __restrict__ bh1,
    const float* __restrict__ Wh2, const float* __restrict__ bh2,
    const float* __restrict__ Wr1, const float* __restrict__ br1,
    const float* __restrict__ Wr2, const float* __restrict__ br2,
    float* __restrict__ block_sums, int N)
{
    const int p = blockIdx.x * blockDim.x + threadIdx.x;   // pair index
    const int npairs = N >> 1;                              // N is even (2^21)

    float cost = 0.0f;
    if (p < npairs) {
        const f32x2 tgt0 = ((const f32x2*)omega)[p];        // tasks 2p, 2p+1 (row 0)
        const f32x2 tgt1 = ((const f32x2*)(omega + N))[p];  // row 1
        f32x2 sv0 = sp(s0p[0]);
        f32x2 sv1 = sp(s0p[1]);

        // human layer 1: cols 0,1 multiply constant s_star -> hoist out of loop
        const float w02 = Wh1[2],  w03 = Wh1[3];
        const float w12 = Wh1[6],  w13 = Wh1[7];
        const float w22 = Wh1[10], w23 = Wh1[11];
        const float w32 = Wh1[14], w33 = Wh1[15];
        const f32x2 hp0 = sp(Wh1[0])  * tgt0 + sp(Wh1[1])  * tgt1 + sp(bh1[0]);
        const f32x2 hp1 = sp(Wh1[4])  * tgt0 + sp(Wh1[5])  * tgt1 + sp(bh1[1]);
        const f32x2 hp2 = sp(Wh1[8])  * tgt0 + sp(Wh1[9])  * tgt1 + sp(bh1[2]);
        const f32x2 hp3 = sp(Wh1[12]) * tgt0 + sp(Wh1[13]) * tgt1 + sp(bh1[3]);
        const float u0 = Wh2[0], u1 = Wh2[1], u2 = Wh2[2], u3 = Wh2[3], ub = bh2[0];
        const float r00 = Wr1[0], r01 = Wr1[1], r02 = Wr1[2], rb0 = br1[0];
        const float r10 = Wr1[3], r11 = Wr1[4], r12 = Wr1[5], rb1 = br1[1];
        const float r20 = Wr1[6], r21 = Wr1[7], r22 = Wr1[8], rb2 = br1[2];
        const float v0 = Wr2[0], v1 = Wr2[1], v2 = Wr2[2], vb = br2[0];

        f32x2 err = sp(0.0f), eff = sp(0.0f);
        #pragma unroll
        for (int t = 0; t < NSTEPS - 1; ++t) {
            f32x2 e0 = tgt0 - sv0;
            f32x2 e1 = tgt1 - sv1;
            err += sp(10.0f) * e0 * e0 + e1 * e1;
            f32x2 h0 = ftanh2(hp0 + sp(w02) * sv0 + sp(w03) * sv1);
            f32x2 h1 = ftanh2(hp1 + sp(w12) * sv0 + sp(w13) * sv1);
            f32x2 h2 = ftanh2(hp2 + sp(w22) * sv0 + sp(w23) * sv1);
            f32x2 h3 = ftanh2(hp3 + sp(w32) * sv0 + sp(w33) * sv1);
            f32x2 z  = sp(ub) + sp(u0) * h0 + sp(u1) * h1 + sp(u2) * h2 + sp(u3) * h3;
            eff += z * z;
            f32x2 q0 = ftanh2(sp(rb0) + sp(r00) * sv0 + sp(r01) * sv1 + sp(r02) * z);
            f32x2 q1 = ftanh2(sp(rb1) + sp(r10) * sv0 + sp(r11) * sv1 + sp(r12) * z);
            f32x2 q2 = ftanh2(sp(rb2) + sp(r20) * sv0 + sp(r21) * sv1 + sp(r22) * z);
            f32x2 a  = sp(vb) + sp(v0) * q0 + sp(v1) * q1 + sp(v2) * q2;
            f32x2 ns0 = sv0 + sp(DT_F) * sv1;   // uses OLD sv1
            f32x2 ns1 = sv1 + sp(DT_F) * a;
            sv0 = ns0; sv1 = ns1;
        }
        f32x2 e0 = tgt0 - sv0;
        f32x2 e1 = tgt1 - sv1;
        err += sp(10.0f) * e0 * e0 + e1 * e1;   // terminal cost
        f32x2 tot = err + eff;
        cost = tot.x + tot.y;
    }

    // wave (64-lane) reduce, then cross-wave via LDS
    #pragma unroll
    for (int off = 32; off > 0; off >>= 1)
        cost += __shfl_down(cost, off, 64);
    __shared__ float ws[4];
    const int lane = threadIdx.x & 63;
    const int wid  = threadIdx.x >> 6;
    if (lane == 0) ws[wid] = cost;
    __syncthreads();
    if (threadIdx.x == 0)
        block_sums[blockIdx.x] = ws[0] + ws[1] + ws[2] + ws[3];
}

__global__ __launch_bounds__(1024) void final_reduce(
    const float* __restrict__ block_sums, int nb, int N, float* __restrict__ out)
{
    // nb = 4096 for N=2^21: each of 1024 threads loads exactly one float4 ->
    // fully parallel independent loads (no serial latency chain).
    double s = 0.0;
    const int nb4 = nb >> 2;
    const float4* bs4 = (const float4*)block_sums;
    for (int i = threadIdx.x; i < nb4; i += 1024) {
        float4 v = bs4[i];
        s += (double)v.x + (double)v.y + (double)v.z + (double)v.w;
    }
    for (int i = (nb4 << 2) + threadIdx.x; i < nb; i += 1024)
        s += (double)block_sums[i];

    #pragma unroll
    for (int off = 32; off > 0; off >>= 1)
        s += __shfl_down(s, off, 64);
    __shared__ double wsum[16];
    const int lane = threadIdx.x & 63;
    const int wid  = threadIdx.x >> 6;
    if (lane == 0) wsum[wid] = s;
    __syncthreads();
    if (threadIdx.x == 0) {
        double tot = 0.0;
        #pragma unroll
        for (int w = 0; w < 16; ++w) tot += wsum[w];
        out[0] = (float)(tot / (double)N);
    }
}

extern "C" void kernel_launch(void* const* d_in, const int* in_sizes, int n_in,
                              void* d_out, int out_size, void* d_ws, size_t ws_size,
                              hipStream_t stream) {
    const float* omega = (const float*)d_in[0];
    const float* s0    = (const float*)d_in[1];
    const float* Wh1   = (const float*)d_in[2];
    const float* bh1   = (const float*)d_in[3];
    const float* Wh2   = (const float*)d_in[4];
    const float* bh2   = (const float*)d_in[5];
    const float* Wr1   = (const float*)d_in[6];
    const float* br1   = (const float*)d_in[7];
    const float* Wr2   = (const float*)d_in[8];
    const float* br2   = (const float*)d_in[9];
    float* out = (float*)d_out;
    float* block_sums = (float*)d_ws;   // blocks * 4 bytes << ws_size

    const int N = in_sizes[0] / 2;
    const int npairs = N >> 1;
    const int blocks = (npairs + 255) / 256;   // 4096 for N=2^21
    rollout_kernel<<<blocks, 256, 0, stream>>>(omega, s0, Wh1, bh1, Wh2, bh2,
                                               Wr1, br1, Wr2, br2, block_sums, N);
    final_reduce<<<1, 1024, 0, stream>>>(block_sums, blocks, N, out);
}

// Round 4
// 98.895 us; speedup vs baseline: 1.9398x; 1.5329x over previous
//
#include <hip/hip_runtime.h>

#define NSTEPS 21
#define DT_F 0.05f
#define NX 1024
#define NY 4
#define MM_BLOCKS 2048   // K1/K3 grid
// ws layout (float indices)
#define WS_PART   0       // 4 arrays of MM_BLOCKS: xmn, xmx, ymn, ymx
#define WS_RANGES 8192    // 4 floats: xmn, xmx, ymn, ymx (reduced)
#define WS_TABLE  8704    // NX*NY floats (16B-aligned offset)
#define WS_PSUM   12800   // MM_BLOCKS floats

#define BIGF 3.4e38f

// tanh(x) = 1 - 2/(1 + 2^(x*2*log2 e)); saturates correctly at +/-inf.
__device__ __forceinline__ float fast_tanh(float x) {
    float e = __builtin_amdgcn_exp2f(x * 2.885390081777927f);
    return 1.0f - 2.0f * __builtin_amdgcn_rcpf(1.0f + e);
}

// Exact scalar rollout (same math as the absmax=0.0 round-2 kernel).
__device__ float rollout_cost(float tgt0, float tgt1, float sv0, float sv1,
    const float* __restrict__ Wh1, const float* __restrict__ bh1,
    const float* __restrict__ Wh2, const float* __restrict__ bh2,
    const float* __restrict__ Wr1, const float* __restrict__ br1,
    const float* __restrict__ Wr2, const float* __restrict__ br2)
{
    const float w02 = Wh1[2],  w03 = Wh1[3];
    const float w12 = Wh1[6],  w13 = Wh1[7];
    const float w22 = Wh1[10], w23 = Wh1[11];
    const float w32 = Wh1[14], w33 = Wh1[15];
    const float hp0 = Wh1[0]  * tgt0 + Wh1[1]  * tgt1 + bh1[0];
    const float hp1 = Wh1[4]  * tgt0 + Wh1[5]  * tgt1 + bh1[1];
    const float hp2 = Wh1[8]  * tgt0 + Wh1[9]  * tgt1 + bh1[2];
    const float hp3 = Wh1[12] * tgt0 + Wh1[13] * tgt1 + bh1[3];
    const float u0 = Wh2[0], u1 = Wh2[1], u2 = Wh2[2], u3 = Wh2[3], ub = bh2[0];
    const float r00 = Wr1[0], r01 = Wr1[1], r02 = Wr1[2], rb0 = br1[0];
    const float r10 = Wr1[3], r11 = Wr1[4], r12 = Wr1[5], rb1 = br1[1];
    const float r20 = Wr1[6], r21 = Wr1[7], r22 = Wr1[8], rb2 = br1[2];
    const float v0 = Wr2[0], v1 = Wr2[1], v2 = Wr2[2], vb = br2[0];

    float err = 0.0f, eff = 0.0f;
    #pragma unroll
    for (int t = 0; t < NSTEPS - 1; ++t) {
        float e0 = tgt0 - sv0;
        float e1 = tgt1 - sv1;
        err += 10.0f * e0 * e0 + e1 * e1;
        float h0 = fast_tanh(hp0 + w02 * sv0 + w03 * sv1);
        float h1 = fast_tanh(hp1 + w12 * sv0 + w13 * sv1);
        float h2 = fast_tanh(hp2 + w22 * sv0 + w23 * sv1);
        float h3 = fast_tanh(hp3 + w32 * sv0 + w33 * sv1);
        float z  = ub + u0 * h0 + u1 * h1 + u2 * h2 + u3 * h3;
        eff += z * z;
        float q0 = fast_tanh(rb0 + r00 * sv0 + r01 * sv1 + r02 * z);
        float q1 = fast_tanh(rb1 + r10 * sv0 + r11 * sv1 + r12 * z);
        float q2 = fast_tanh(rb2 + r20 * sv0 + r21 * sv1 + r22 * z);
        float a  = vb + v0 * q0 + v1 * q1 + v2 * q2;
        float ns0 = sv0 + DT_F * sv1;   // uses OLD sv1
        float ns1 = sv1 + DT_F * a;
        sv0 = ns0; sv1 = ns1;
    }
    float e0 = tgt0 - sv0;
    float e1 = tgt1 - sv1;
    err += 10.0f * e0 * e0 + e1 * e1;
    return err + eff;
}

// ---------- K1: per-block min/max partials of omega rows ----------
__global__ __launch_bounds__(256) void minmax_kernel(
    const float* __restrict__ omega, int N, float* __restrict__ ws)
{
    const int gtid = blockIdx.x * 256 + threadIdx.x;
    const int stride = gridDim.x * 256;
    float xmn = BIGF, xmx = -BIGF, ymn = BIGF, ymx = -BIGF;
    const float4* r0 = (const float4*)omega;
    const float4* r1 = (const float4*)(omega + N);
    const int n4 = N >> 2;
    for (int i = gtid; i < n4; i += stride) {
        float4 a = r0[i];
        xmn = fminf(xmn, fminf(fminf(a.x, a.y), fminf(a.z, a.w)));
        xmx = fmaxf(xmx, fmaxf(fmaxf(a.x, a.y), fmaxf(a.z, a.w)));
        float4 b = r1[i];
        ymn = fminf(ymn, fminf(fminf(b.x, b.y), fminf(b.z, b.w)));
        ymx = fmaxf(ymx, fmaxf(fmaxf(b.x, b.y), fmaxf(b.z, b.w)));
    }
    #pragma unroll
    for (int off = 32; off > 0; off >>= 1) {
        xmn = fminf(xmn, __shfl_down(xmn, off, 64));
        xmx = fmaxf(xmx, __shfl_down(xmx, off, 64));
        ymn = fminf(ymn, __shfl_down(ymn, off, 64));
        ymx = fmaxf(ymx, __shfl_down(ymx, off, 64));
    }
    __shared__ float s[4][4];
    const int lane = threadIdx.x & 63, wid = threadIdx.x >> 6;
    if (lane == 0) { s[wid][0] = xmn; s[wid][1] = xmx; s[wid][2] = ymn; s[wid][3] = ymx; }
    __syncthreads();
    if (threadIdx.x == 0) {
        float a0 = fminf(fminf(s[0][0], s[1][0]), fminf(s[2][0], s[3][0]));
        float a1 = fmaxf(fmaxf(s[0][1], s[1][1]), fmaxf(s[2][1], s[3][1]));
        float a2 = fminf(fminf(s[0][2], s[1][2]), fminf(s[2][2], s[3][2]));
        float a3 = fmaxf(fmaxf(s[0][3], s[1][3]), fmaxf(s[2][3], s[3][3]));
        ws[WS_PART + blockIdx.x]                 = a0;
        ws[WS_PART + MM_BLOCKS + blockIdx.x]     = a1;
        ws[WS_PART + 2 * MM_BLOCKS + blockIdx.x] = a2;
        ws[WS_PART + 3 * MM_BLOCKS + blockIdx.x] = a3;
    }
}

// ---------- K2: reduce ranges (redundant per block) + build cost table ----------
__global__ __launch_bounds__(256) void table_kernel(
    float* __restrict__ ws, const float* __restrict__ s0p,
    const float* __restrict__ Wh1, const float* __restrict__ bh1,
    const float* __restrict__ Wh2, const float* __restrict__ bh2,
    const float* __restrict__ Wr1, const float* __restrict__ br1,
    const float* __restrict__ Wr2, const float* __restrict__ br2)
{
    float xmn = BIGF, xmx = -BIGF, ymn = BIGF, ymx = -BIGF;
    for (int i = threadIdx.x; i < MM_BLOCKS; i += 256) {
        xmn = fminf(xmn, ws[WS_PART + i]);
        xmx = fmaxf(xmx, ws[WS_PART + MM_BLOCKS + i]);
        ymn = fminf(ymn, ws[WS_PART + 2 * MM_BLOCKS + i]);
        ymx = fmaxf(ymx, ws[WS_PART + 3 * MM_BLOCKS + i]);
    }
    #pragma unroll
    for (int off = 32; off > 0; off >>= 1) {
        xmn = fminf(xmn, __shfl_down(xmn, off, 64));
        xmx = fmaxf(xmx, __shfl_down(xmx, off, 64));
        ymn = fminf(ymn, __shfl_down(ymn, off, 64));
        ymx = fmaxf(ymx, __shfl_down(ymx, off, 64));
    }
    __shared__ float s[4][4];
    __shared__ float fin[4];
    const int lane = threadIdx.x & 63, wid = threadIdx.x >> 6;
    if (lane == 0) { s[wid][0] = xmn; s[wid][1] = xmx; s[wid][2] = ymn; s[wid][3] = ymx; }
    __syncthreads();
    if (threadIdx.x == 0) {
        fin[0] = fminf(fminf(s[0][0], s[1][0]), fminf(s[2][0], s[3][0]));
        fin[1] = fmaxf(fmaxf(s[0][1], s[1][1]), fmaxf(s[2][1], s[3][1]));
        fin[2] = fminf(fminf(s[0][2], s[1][2]), fminf(s[2][2], s[3][2]));
        fin[3] = fmaxf(fmaxf(s[0][3], s[1][3]), fmaxf(s[2][3], s[3][3]));
        if (blockIdx.x == 0) {
            ws[WS_RANGES + 0] = fin[0]; ws[WS_RANGES + 1] = fin[1];
            ws[WS_RANGES + 2] = fin[2]; ws[WS_RANGES + 3] = fin[3];
        }
    }
    __syncthreads();
    xmn = fin[0]; xmx = fin[1]; ymn = fin[2]; ymx = fin[3];

    const int gid = blockIdx.x * 256 + threadIdx.x;   // 0 .. NX*NY-1
    const int ix = gid >> 2;    // NY == 4
    const int iy = gid & 3;
    const float dx = xmx - xmn, dy = ymx - ymn;
    const float x = xmn + (dx > 0.0f ? dx * ((float)ix * (1.0f / (NX - 1))) : 0.0f);
    const float y = ymn + (dy > 0.0f ? dy * ((float)iy * (1.0f / (NY - 1))) : 0.0f);
    const float c = rollout_cost(x, y, s0p[0], s0p[1],
                                 Wh1, bh1, Wh2, bh2, Wr1, br1, Wr2, br2);
    ws[WS_TABLE + gid] = c;
}

// ---------- K3: bilinear interp from LDS table + block partial sums ----------
__global__ __launch_bounds__(256) void interp_kernel(
    const float* __restrict__ omega, int N, const float* __restrict__ ws,
    float* __restrict__ psum)
{
    __shared__ float tab[NX * NY];
    {
        const float4* tg = (const float4*)(ws + WS_TABLE);
        float4* tl = (float4*)tab;
        for (int i = threadIdx.x; i < (NX * NY) / 4; i += 256) tl[i] = tg[i];
    }
    const float xmn = ws[WS_RANGES + 0], xmx = ws[WS_RANGES + 1];
    const float ymn = ws[WS_RANGES + 2], ymx = ws[WS_RANGES + 3];
    const float dx = xmx - xmn, dy = ymx - ymn;
    const float invx = dx > 0.0f ? (float)(NX - 1) / dx : 0.0f;
    const float invy = dy > 0.0f ? (float)(NY - 1) / dy : 0.0f;
    __syncthreads();

    float acc = 0.0f;
    const int gtid = blockIdx.x * 256 + threadIdx.x;
    const int stride = gridDim.x * 256;
    const float4* r0 = (const float4*)omega;
    const float4* r1 = (const float4*)(omega + N);
    const int n4 = N >> 2;
    for (int i = gtid; i < n4; i += stride) {
        float4 xs = r0[i];
        float4 ys = r1[i];
        float xv[4] = {xs.x, xs.y, xs.z, xs.w};
        float yv[4] = {ys.x, ys.y, ys.z, ys.w};
        #pragma unroll
        for (int k = 0; k < 4; ++k) {
            float fx = fminf(fmaxf((xv[k] - xmn) * invx, 0.0f), (float)(NX - 1));
            float fy = fminf(fmaxf((yv[k] - ymn) * invy, 0.0f), (float)(NY - 1));
            int ix = min((int)fx, NX - 2);
            int iy = min((int)fy, NY - 2);
            float tx = fx - (float)ix;
            float ty = fy - (float)iy;
            int base = (ix << 2) + iy;   // NY == 4
            float c00 = tab[base],     c01 = tab[base + 1];
            float c10 = tab[base + 4], c11 = tab[base + 5];
            float c0 = c00 + tx * (c10 - c00);
            float c1 = c01 + tx * (c11 - c01);
            acc += c0 + ty * (c1 - c0);
        }
    }
    #pragma unroll
    for (int off = 32; off > 0; off >>= 1)
        acc += __shfl_down(acc, off, 64);
    __shared__ float wsum[4];
    const int lane = threadIdx.x & 63, wid = threadIdx.x >> 6;
    if (lane == 0) wsum[wid] = acc;
    __syncthreads();
    if (threadIdx.x == 0)
        psum[blockIdx.x] = wsum[0] + wsum[1] + wsum[2] + wsum[3];
}

// ---------- K4: final reduce ----------
__global__ __launch_bounds__(1024) void final_reduce(
    const float* __restrict__ block_sums, int nb, int N, float* __restrict__ out)
{
    double s = 0.0;
    const int nb4 = nb >> 2;
    const float4* bs4 = (const float4*)block_sums;
    for (int i = threadIdx.x; i < nb4; i += 1024) {
        float4 v = bs4[i];
        s += (double)v.x + (double)v.y + (double)v.z + (double)v.w;
    }
    for (int i = (nb4 << 2) + threadIdx.x; i < nb; i += 1024)
        s += (double)block_sums[i];
    #pragma unroll
    for (int off = 32; off > 0; off >>= 1)
        s += __shfl_down(s, off, 64);
    __shared__ double wsum[16];
    const int lane = threadIdx.x & 63, wid = threadIdx.x >> 6;
    if (lane == 0) wsum[wid] = s;
    __syncthreads();
    if (threadIdx.x == 0) {
        double tot = 0.0;
        #pragma unroll
        for (int w = 0; w < 16; ++w) tot += wsum[w];
        out[0] = (float)(tot / (double)N);
    }
}

extern "C" void kernel_launch(void* const* d_in, const int* in_sizes, int n_in,
                              void* d_out, int out_size, void* d_ws, size_t ws_size,
                              hipStream_t stream) {
    const float* omega = (const float*)d_in[0];
    const float* s0    = (const float*)d_in[1];
    const float* Wh1   = (const float*)d_in[2];
    const float* bh1   = (const float*)d_in[3];
    const float* Wh2   = (const float*)d_in[4];
    const float* bh2   = (const float*)d_in[5];
    const float* Wr1   = (const float*)d_in[6];
    const float* br1   = (const float*)d_in[7];
    const float* Wr2   = (const float*)d_in[8];
    const float* br2   = (const float*)d_in[9];
    float* out = (float*)d_out;
    float* ws  = (float*)d_ws;   // < 64 KB used

    const int N = in_sizes[0] / 2;

    minmax_kernel<<<MM_BLOCKS, 256, 0, stream>>>(omega, N, ws);
    table_kernel<<<(NX * NY) / 256, 256, 0, stream>>>(ws, s0, Wh1, bh1, Wh2, bh2,
                                                      Wr1, br1, Wr2, br2);
    interp_kernel<<<MM_BLOCKS, 256, 0, stream>>>(omega, N, ws, ws + WS_PSUM);
    final_reduce<<<1, 1024, 0, stream>>>(ws + WS_PSUM, MM_BLOCKS, N, out);
}